// Round 16
// baseline (8255.886 us; speedup 1.0000x reference)
//
#include <hip/hip_runtime.h>
#include <hip/hip_bf16.h>

typedef __attribute__((ext_vector_type(8))) short bhalf8;
typedef __attribute__((ext_vector_type(4))) float fvec4;
typedef __attribute__((ext_vector_type(4))) unsigned u32x4;

static __device__ __forceinline__ unsigned short f2bf(float f) {
  unsigned u = __builtin_bit_cast(unsigned, f);
  u = (u + 0x7fffu + ((u >> 16) & 1u)) >> 16;   // round-to-nearest-even
  return (unsigned short)u;
}
static __device__ __forceinline__ float tanh_fast(float x) {
  x = fminf(12.f, fmaxf(-12.f, x));
  float e = __expf(2.f * x);
  return (e - 1.f) / (e + 1.f);
}
static __device__ __forceinline__ fvec4 tanh4(fvec4 v) {
  fvec4 r;
  r[0] = tanh_fast(v[0]); r[1] = tanh_fast(v[1]);
  r[2] = tanh_fast(v[2]); r[3] = tanh_fast(v[3]);
  return r;
}
static __device__ __forceinline__ bhalf8 load_w8(const float* p) {
  fvec4 a = *(const fvec4*)p;
  fvec4 b = *(const fvec4*)(p + 4);
  bhalf8 r;
  r[0] = (short)f2bf(a[0]); r[1] = (short)f2bf(a[1]);
  r[2] = (short)f2bf(a[2]); r[3] = (short)f2bf(a[3]);
  r[4] = (short)f2bf(b[0]); r[5] = (short)f2bf(b[1]);
  r[6] = (short)f2bf(b[2]); r[7] = (short)f2bf(b[3]);
  return r;
}

// ---- fabric-coherent (sc0 sc1): the only proven tier (r4/r9/r12/r15). SESSION
// ---- RULES: (1) no asm-load dest window across a GEMM (r6/r8) — glls immune;
// ---- (2) staging via global_load_lds; (3) flags/polls fused-vmcnt sc0sc1;
// ---- (4) one poll/drain/flag per step (r13); (5) group staging synchronized (r14);
// ---- (6) __launch_bounds__ 2nd arg is BLOCKS/CU (CUDA semantics — r10 evidence).
static __device__ __forceinline__ void st_f32_coh(float* p, float v) {
  asm volatile("global_store_dword %0, %1, off sc0 sc1" :: "v"(p), "v"(v) : "memory");
}
static __device__ __forceinline__ void st_u32_coh(unsigned* p, unsigned v) {
  asm volatile("global_store_dword %0, %1, off sc0 sc1" :: "v"(p), "v"(v) : "memory");
}
static __device__ __forceinline__ void st16_coh(void* p, u32x4 v) {
  asm volatile("global_store_dwordx4 %0, %1, off sc0 sc1" :: "v"(p), "v"(v) : "memory");
}
static __device__ __forceinline__ unsigned ld_u32_coh(const unsigned* p) {
  unsigned v;
  asm volatile("global_load_dword %0, %1, off sc0 sc1\n\ts_waitcnt vmcnt(0)"
               : "=v"(v) : "v"(p) : "memory");
  return v;
}
static __device__ __forceinline__ float ld_f32_coh(const float* p) {
  float v;
  asm volatile("global_load_dword %0, %1, off sc0 sc1\n\ts_waitcnt vmcnt(0)"
               : "=v"(v) : "v"(p) : "memory");
  return v;
}
static __device__ __forceinline__ void gll16_coh(const void* g, void* lds) {
  __builtin_amdgcn_global_load_lds(
      (const __attribute__((address_space(1))) void*)g,
      (__attribute__((address_space(3))) void*)lds, 16, 0, 0x11);
}

#define MFMA16(a, b, c) __builtin_amdgcn_mfma_f32_16x16x32_bf16((a), (b), (c), 0, 0, 0)

// Persistent kernel, 256 WGs x 512 thr (8 waves, 2/SIMD), 1 WG/CU (160K LDS) ->
// grid HW-resident, spin safe. WG=(grp: 32 batch rows, memb: 64 H-cols).
// r15 protocol; K-SPLIT-8: wave w holds K-slice [w*128,+128) of Wrec and [w*32,+32)
// of Win for all 4 n-tiles (160 weight VGPRs/lane — fits the 2-wave/SIMD budget).
// 2 waves/SIMD double memory-latency hiding during staging and GEMM.
extern "C" __global__ void __launch_bounds__(512, 1)
alarm_rnn_persist(const float* __restrict__ X, const float* __restrict__ Win1,
                  const float* __restrict__ bin1, const float* __restrict__ Wrec1,
                  const float* __restrict__ Win2, const float* __restrict__ bin2,
                  const float* __restrict__ Wrec2, const float* __restrict__ Wout,
                  const float* __restrict__ bout, float* __restrict__ out,
                  unsigned* flags, unsigned short* gbuf0, unsigned short* gbuf1,
                  unsigned short* z2b0, unsigned short* z2b1, float* z1buf)
{
  constexpr int kL = 512, kI = 256, kH = 1024;
  // LDS: [0,64K) z12 stage -> z1 partials -> transpose tiles
  //      [64K,128K) z2 stage -> z2 partials
  //      [128K,160K) X ping-pong (2 x 16K)
  extern __shared__ char smem[];

  const int tid = threadIdx.x, bid = blockIdx.x;
  const int grp = bid >> 4, memb = bid & 15;
  const int lane = tid & 63, w = tid >> 6;          // 8 waves
  const int row16 = lane & 15, kq = lane >> 4;
  const int sw = (row16 & 7) << 4;
  const int ntw = w >> 1, mtw = w & 1;              // finalize tile of this wave
  const int hcolf = memb * 64 + ntw * 16 + row16;   // finalize/store col
  const int brow0 = grp * 32;

  // ---- weights, K-split-8: wave w holds K-slice [w*128,+128) (Wrec) / [w*32,+32)
  // ---- (Win) for ALL 4 n-tiles. 40 bhalf8 = 160 VGPRs.
  bhalf8 w1[16], w2[16], wi1[4], wi2[4];
#pragma unroll
  for (int nt = 0; nt < 4; ++nt) {
    const size_t c = (size_t)(memb * 64 + nt * 16 + row16);
#pragma unroll
    for (int kk = 0; kk < 4; ++kk) {
      w1[nt * 4 + kk] = load_w8(Wrec1 + c * kH + w * 128 + kk * 32 + kq * 8);
      w2[nt * 4 + kk] = load_w8(Wrec2 + c * kH + w * 128 + kk * 32 + kq * 8);
    }
    wi1[nt] = load_w8(Win1 + c * kI + w * 32 + kq * 8);
    wi2[nt] = load_w8(Win2 + c * kI + w * 32 + kq * 8);
  }
  const float bv1 = bin1[hcolf];
  const float bv2 = bin2[hcolf];
  fvec4 z2c = {0.f, 0.f, 0.f, 0.f};  // own finalize-tile z2 slice

  // ---- prologue: stage X(0) -> Xbuf0, X(1) -> Xbuf1 (512 thr: 16/row) ----
  {
    int r = tid >> 4, t = tid & 15;
#pragma unroll
    for (int p = 0; p < 2; ++p) {
      const float* xp = X + (size_t)(brow0 + r) * (kL * kI) + (size_t)p * kI;
#pragma unroll
      for (int j = 0; j < 4; ++j) {
        fvec4 v = *(const fvec4*)(xp + t * 4 + j * 64);
        ushort4 pk;
        pk.x = f2bf(v[0]); pk.y = f2bf(v[1]); pk.z = f2bf(v[2]); pk.w = f2bf(v[3]);
        int i0 = t * 4 + j * 64;
        *(ushort4*)(smem + 131072 + p * 16384 + (r << 9) + ((i0 * 2) ^ ((r & 7) << 4))) = pk;
      }
    }
  }
  __syncthreads();

  for (int l = 0; l < kL; ++l) {
    const bool even = ((l & 1) == 0);
    const int e = l >> 1;

    // ---- A1: issue z12 (and z2 on even) global->LDS; member-staggered ----
    {
      const unsigned short* zsrc = (l & 1) ? gbuf1 : gbuf0;
#pragma unroll
      for (int it = 0; it < 8; ++it) {
        int ci = ((it + memb) & 7) * 8 + w;          // 1KB chunk id 0..63
        int c = (ci << 6) + lane;                    // 16B unit id
        int r = c >> 7, cbs = (c & 127) * 16;
        gll16_coh((const char*)zsrc + (((size_t)(brow0 + r)) << 11) + (cbs ^ ((r & 7) << 4)),
                  smem + ci * 1024 + lane * 16);
      }
      if (even) {
        const unsigned short* z2src = (e & 1) ? z2b1 : z2b0;
#pragma unroll
        for (int it = 0; it < 8; ++it) {
          int ci = ((it + memb) & 7) * 8 + w;
          int c = (ci << 6) + lane;
          int r = c >> 7, cbs = (c & 127) * 16;
          gll16_coh((const char*)z2src + (((size_t)(brow0 + r)) << 11) + (cbs ^ ((r & 7) << 4)),
                    smem + 65536 + ci * 1024 + lane * 16);
        }
      }
      __builtin_amdgcn_sched_barrier(0);  // keep issues above the MFMA shadow
    }

    // ---- A2: Win*X partials (wave's K=32 slice) under the load shadow ----
    const char* xb = smem + 131072 + ((l & 1) << 14);
    fvec4 acc[8], c2a[8];
#pragma unroll
    for (int t = 0; t < 8; ++t) { acc[t] = {0.f, 0.f, 0.f, 0.f}; c2a[t] = {0.f, 0.f, 0.f, 0.f}; }
    {
      int cbx = w * 64 + kq * 16;
      bhalf8 xa0 = *(const bhalf8*)(xb + (row16 << 9) + (cbx ^ sw));
      bhalf8 xa1 = *(const bhalf8*)(xb + ((16 + row16) << 9) + (cbx ^ sw));
#pragma unroll
      for (int nt = 0; nt < 4; ++nt) {
        acc[nt * 2] = MFMA16(xa0, wi1[nt], acc[nt * 2]);
        acc[nt * 2 + 1] = MFMA16(xa1, wi1[nt], acc[nt * 2 + 1]);
      }
      if (even) {
#pragma unroll
        for (int nt = 0; nt < 4; ++nt) {
          c2a[nt * 2] = MFMA16(xa0, wi2[nt], c2a[nt * 2]);
          c2a[nt * 2 + 1] = MFMA16(xa1, wi2[nt], c2a[nt * 2 + 1]);
        }
      }
    }
    // ---- A3: staged data complete -> visible to all waves ----
    asm volatile("s_waitcnt vmcnt(0)" ::: "memory");
    __builtin_amdgcn_sched_barrier(0);
    __syncthreads();  // #1

    // ---- B1: Wrec1*z12 partial (wave's K=128 slice; A-fragments read once) ----
#pragma unroll
    for (int kk = 0; kk < 4; ++kk) {
      int cb = (w * 4 + kk) * 64 + kq * 16;
      bhalf8 a0 = *(const bhalf8*)(smem + (row16 << 11) + (cb ^ sw));
      bhalf8 a1 = *(const bhalf8*)(smem + ((16 + row16) << 11) + (cb ^ sw));
#pragma unroll
      for (int nt = 0; nt < 4; ++nt) {
        acc[nt * 2] = MFMA16(a0, w1[nt * 4 + kk], acc[nt * 2]);
        acc[nt * 2 + 1] = MFMA16(a1, w1[nt * 4 + kk], acc[nt * 2 + 1]);
      }
    }
    // ---- B2 (even): Wrec2*z2 partial ----
    if (even) {
#pragma unroll
      for (int kk = 0; kk < 4; ++kk) {
        int cb = (w * 4 + kk) * 64 + kq * 16;
        bhalf8 a0 = *(const bhalf8*)(smem + 65536 + (row16 << 11) + (cb ^ sw));
        bhalf8 a1 = *(const bhalf8*)(smem + 65536 + ((16 + row16) << 11) + (cb ^ sw));
#pragma unroll
        for (int nt = 0; nt < 4; ++nt) {
          c2a[nt * 2] = MFMA16(a0, w2[nt * 4 + kk], c2a[nt * 2]);
          c2a[nt * 2 + 1] = MFMA16(a1, w2[nt * 4 + kk], c2a[nt * 2 + 1]);
        }
      }
    }

    // ---- R1: partials -> LDS (z1 into z12 region, z2 into z2 region) ----
    __syncthreads();  // #2: all GEMM reads of staged tiles done
#pragma unroll
    for (int t8 = 0; t8 < 8; ++t8) {
      int base = (t8 * 8 + w) << 10;
      fvec4 v = acc[t8];
#pragma unroll
      for (int i = 0; i < 4; ++i)
        *(float*)(smem + base + (((kq * 4 + i) * 16 + row16) << 2)) = v[i];
      if (even) {
        fvec4 v2 = c2a[t8];
#pragma unroll
        for (int i = 0; i < 4; ++i)
          *(float*)(smem + 65536 + base + (((kq * 4 + i) * 16 + row16) << 2)) = v2[i];
      }
    }
    __syncthreads();  // #3: partials visible

    // ---- R2: finalize own tile t8 = w (nt=w>>1, mt=w&1): sum 8 partials + bias ----
    fvec4 s0 = {0.f, 0.f, 0.f, 0.f};
#pragma unroll
    for (int ws = 0; ws < 8; ++ws) {
      int b = (w * 8 + ws) << 10;
#pragma unroll
      for (int i = 0; i < 4; ++i)
        s0[i] += *(const float*)(smem + b + (((kq * 4 + i) * 16 + row16) << 2));
    }
#pragma unroll
    for (int i = 0; i < 4; ++i) s0[i] += bv1;
    fvec4 z1n = tanh4(s0);
    if (even) {
      fvec4 t0 = {0.f, 0.f, 0.f, 0.f};
#pragma unroll
      for (int ws = 0; ws < 8; ++ws) {
        int b = 65536 + ((w * 8 + ws) << 10);
#pragma unroll
        for (int i = 0; i < 4; ++i)
          t0[i] += *(const float*)(smem + b + (((kq * 4 + i) * 16 + row16) << 2));
      }
#pragma unroll
      for (int i = 0; i < 4; ++i) t0[i] += bv2;
      z2c = tanh4(t0);
    }
    __syncthreads();  // #4: partial reads done -> region reusable for transpose

    // ---- C: coalesced publish via transpose tiles ([0,4K) z12, [4K,8K) z2) ----
    if (l < kL - 1) {
      const int cb2 = (ntw * 16 + row16) * 2;
#pragma unroll
      for (int i = 0; i < 4; ++i) {
        int r0 = mtw * 16 + kq * 4 + i;
        *(unsigned short*)(smem + r0 * 128 + (cb2 ^ ((r0 & 7) << 4))) = f2bf(z1n[i] + z2c[i]);
        if (even)
          *(unsigned short*)(smem + 4096 + r0 * 128 + (cb2 ^ ((r0 & 7) << 4))) = f2bf(z2c[i]);
      }
      __syncthreads();  // #5: transpose tiles complete
      if (tid < 256) {
        int r = tid >> 3, s8 = tid & 7;
        u32x4 v = *(const u32x4*)(smem + r * 128 + ((s8 * 16) ^ ((r & 7) << 4)));
        unsigned short* dst = (l & 1) ? gbuf0 : gbuf1;
        st16_coh((char*)dst + (((size_t)(brow0 + r)) << 11) + memb * 128 + s8 * 16, v);
      } else if (even) {
        int t2 = tid - 256, r = t2 >> 3, s8 = t2 & 7;
        u32x4 v2 = *(const u32x4*)(smem + 4096 + r * 128 + ((s8 * 16) ^ ((r & 7) << 4)));
        unsigned short* z2dst = (e & 1) ? z2b0 : z2b1;
        st16_coh((char*)z2dst + (((size_t)(brow0 + r)) << 11) + memb * 128 + s8 * 16, v2);
      }
    } else {
      // final step: f32 z1, scattered (runs once; epilogue reads it back)
#pragma unroll
      for (int i = 0; i < 4; ++i)
        st_f32_coh(z1buf + (size_t)(brow0 + mtw * 16 + kq * 4 + i) * kH + hcolf, z1n[i]);
    }
    asm volatile("s_waitcnt vmcnt(0)" ::: "memory");
    __syncthreads();  // #6: all exchange stores drained
    if (tid == 0) st_u32_coh(flags + grp * 16 + memb, (unsigned)(l + 1));

    // ---- D: X(l+2) -> Xbuf[l&1] (post-flag slack; normal cached loads) ----
    if (l + 2 < kL) {
      int r = tid >> 4, t = tid & 15;
      const float* xp = X + (size_t)(brow0 + r) * (kL * kI) + (size_t)(l + 2) * kI;
#pragma unroll
      for (int j = 0; j < 4; ++j) {
        fvec4 v = *(const fvec4*)(xp + t * 4 + j * 64);
        ushort4 pk;
        pk.x = f2bf(v[0]); pk.y = f2bf(v[1]); pk.z = f2bf(v[2]); pk.w = f2bf(v[3]);
        int i0 = t * 4 + j * 64;
        *(ushort4*)(smem + 131072 + ((l & 1) << 14) + (r << 9) + ((i0 * 2) ^ ((r & 7) << 4))) = pk;
      }
    }

    // ---- F: poll sibling flags for step l+1 ----
    {
      const unsigned tgt = (unsigned)(l + 1);
      const unsigned* fp = flags + grp * 16 + (lane & 15);
      for (;;) {
        unsigned v = (lane < 16) ? ld_u32_coh(fp) : tgt;
        bool ok = (lane >= 16) || ((lane & 15) == memb) || (v >= tgt);
        if (__all(ok)) break;
        __builtin_amdgcn_s_sleep(1);
      }
      __builtin_amdgcn_sched_barrier(0);
    }
  }

  // ---- epilogue: out[b] = tanh(z1[b,:] . Wout + bout), one WG per group ----
  if (memb == 0) {
    int r = tid >> 4, q = tid & 15;
    const float* zr = z1buf + (size_t)(brow0 + r) * kH;
    float s = 0.f;
    for (int h = q * 64; h < q * 64 + 64; ++h) s += ld_f32_coh(zr + h) * Wout[h];
    s += __shfl_xor(s, 1);
    s += __shfl_xor(s, 2);
    s += __shfl_xor(s, 4);
    s += __shfl_xor(s, 8);
    if (q == 0) out[brow0 + r] = tanh_fast(s + bout[0]);
  }
}

extern "C" void kernel_launch(void* const* d_in, const int* in_sizes, int n_in,
                              void* d_out, int out_size, void* d_ws, size_t ws_size,
                              hipStream_t stream) {
  const float* X = (const float*)d_in[0];
  const float* Win1 = (const float*)d_in[1];
  const float* bin1 = (const float*)d_in[2];
  const float* Wrec1 = (const float*)d_in[3];
  const float* Win2 = (const float*)d_in[4];
  const float* bin2 = (const float*)d_in[5];
  const float* Wrec2 = (const float*)d_in[6];
  const float* Wout = (const float*)d_in[7];
  const float* bout = (const float*)d_in[8];
  float* out = (float*)d_out;

  char* ws = (char*)d_ws;
  unsigned* flags = (unsigned*)ws;                                   // 256 dwords
  unsigned short* gbuf0 = (unsigned short*)(ws + 4096);              // 1 MB z12 ping
  unsigned short* gbuf1 = (unsigned short*)(ws + 4096 + (1 << 20));  // 1 MB z12 pong
  unsigned short* z2b0 = (unsigned short*)(ws + 4096 + (2 << 20));   // 1 MB z2 ping
  unsigned short* z2b1 = (unsigned short*)(ws + 4096 + (3 << 20));   // 1 MB z2 pong
  float* z1buf = (float*)(ws + 4096 + (4 << 20));                    // 2 MB final z1 (f32)

  (void)hipMemsetAsync(flags, 0, 4096, stream);
  (void)hipMemsetAsync(gbuf0, 0, (size_t)512 * 1024 * 2, stream);  // z12(l=0) = 0
  (void)hipMemsetAsync(z2b0, 0, (size_t)512 * 1024 * 2, stream);   // z2(l=0)  = 0

  (void)hipFuncSetAttribute((const void*)alarm_rnn_persist,
                            hipFuncAttributeMaxDynamicSharedMemorySize, 163840);

  alarm_rnn_persist<<<dim3(256), dim3(512), 163840, stream>>>(
      X, Win1, bin1, Wrec1, Win2, bin2, Wrec2, Wout, bout, out,
      flags, gbuf0, gbuf1, z2b0, z2b1, z1buf);
}